// Round 2
// baseline (290.198 us; speedup 1.0000x reference)
//
#include <hip/hip_runtime.h>
#include <hip/hip_bf16.h>
#include <math.h>

#define B_   8192
#define F_   48
#define T_   512
#define L_   8
#define NBLK 256
#define THR  512
#define NW   8           // waves per block
#define RPB  32          // rows per block
#define HST  520         // H LDS row stride in shorts (1040B; 65 uint4)
#define ZS   52          // z LDS row stride in floats
#define LINE 32          // dwords per 128B sync line

typedef unsigned short ushort_t;
typedef unsigned int   uint_t;
typedef __attribute__((ext_vector_type(8))) short short8;
typedef __attribute__((ext_vector_type(4))) float f32x4;

#define MFMA(a,b,c) __builtin_amdgcn_mfma_f32_16x16x32_bf16(a,b,c,0,0,0)

__device__ inline ushort_t f2bf(float x) {
    __hip_bfloat16 h = __float2bfloat16(x);
    return *reinterpret_cast<ushort_t*>(&h);
}
__device__ inline short8 negbf(short8 v) {
    short8 r;
    #pragma unroll
    for (int i = 0; i < 8; ++i) r[i] = v[i] ^ (short)0x8000;
    return r;
}
__device__ inline short8 pack8(float4 a, float4 b) {
    short8 r;
    r[0]=(short)f2bf(a.x); r[1]=(short)f2bf(a.y); r[2]=(short)f2bf(a.z); r[3]=(short)f2bf(a.w);
    r[4]=(short)f2bf(b.x); r[5]=(short)f2bf(b.y); r[6]=(short)f2bf(b.z); r[7]=(short)f2bf(b.w);
    return r;
}

__device__ inline float aload(const float* p) {
    return __hip_atomic_load(p, __ATOMIC_RELAXED, __HIP_MEMORY_SCOPE_AGENT);
}
__device__ inline void astore(float* p, float v) {
    __hip_atomic_store(p, v, __ATOMIC_RELAXED, __HIP_MEMORY_SCOPE_AGENT);
}
__device__ inline void afadd(float* p, float v) {
    (void)__hip_atomic_fetch_add(p, v, __ATOMIC_RELAXED, __HIP_MEMORY_SCOPE_AGENT);
}

// --- distributed barrier + all-reduce ------------------------------------
// per sync event s:
//   values: vals + s*16*LINE   : [2 values][8 lines]  (atomic f32 adds, blk&7 spread)
//   counters: cnt8             : [8 lines], cumulative across syncs
//   broadcast: bcF + s*8*LINE  : [8 lines] {flag, v0, v1}
__device__ inline void arrive(float* vbase, uint_t* cnt8, int blk,
                              float v0, float v1, int nv) {
    afadd(vbase + (blk & 7) * LINE, v0);
    if (nv > 1) afadd(vbase + (8 + (blk & 7)) * LINE, v1);
    (void)__hip_atomic_fetch_add(&cnt8[(blk & 7) * LINE], 1u,
                                 __ATOMIC_RELEASE, __HIP_MEMORY_SCOPE_AGENT);
}

__device__ inline float2 collect(uint_t* cnt8, float* vbase, float* bcbase,
                                 uint_t target, int nv) {
    for (;;) {
        uint_t s = 0;
        #pragma unroll
        for (int i = 0; i < 8; ++i)
            s += __hip_atomic_load(&cnt8[i * LINE], __ATOMIC_RELAXED, __HIP_MEMORY_SCOPE_AGENT);
        if (s >= target) break;
        __builtin_amdgcn_s_sleep(1);
    }
    (void)__hip_atomic_load(&cnt8[0], __ATOMIC_ACQUIRE, __HIP_MEMORY_SCOPE_AGENT);
    float v0 = 0.f, v1 = 0.f;
    #pragma unroll
    for (int i = 0; i < 8; ++i) v0 += aload(vbase + i * LINE);
    if (nv > 1) {
        #pragma unroll
        for (int i = 0; i < 8; ++i) v1 += aload(vbase + (8 + i) * LINE);
    }
    #pragma unroll
    for (int j = 0; j < 8; ++j) {
        astore(bcbase + j * LINE + 1, v0);
        astore(bcbase + j * LINE + 2, v1);
    }
    #pragma unroll
    for (int j = 0; j < 8; ++j)
        __hip_atomic_store((uint_t*)(bcbase + j * LINE), 1u,
                           __ATOMIC_RELEASE, __HIP_MEMORY_SCOPE_AGENT);
    return make_float2(v0, v1);
}

__device__ inline float2 waitbc(const float* bcline) {
    while (__hip_atomic_load((const uint_t*)bcline, __ATOMIC_RELAXED,
                             __HIP_MEMORY_SCOPE_AGENT) == 0u)
        __builtin_amdgcn_s_sleep(2);
    (void)__hip_atomic_load((const uint_t*)bcline, __ATOMIC_ACQUIRE,
                            __HIP_MEMORY_SCOPE_AGENT);
    return make_float2(aload(bcline + 1), aload(bcline + 2));
}

// sync region layout (dwords): cnt8[8*LINE] | bcF[16*8*LINE] | vals[16*16*LINE]
#define SYNC_DW ((8 + 16 * 8 + 16 * 16) * LINE)

// ---------- prep: frag-linear bf16 layouts + zero sync region ----------
// Af: [L][tile32][k2(2)][quad4][m16][8]  (fwd B-frags; wave reads 1KiB contiguous)
// At: [L][ft3][ks16][quad4][m16][8]      (bwd B-frags)
// Df: [ft3][ks16][quad4][m16][8]         (final B-frags)
__global__ __launch_bounds__(256) void k_pre(
    const float* __restrict__ Ar, const float* __restrict__ Ai,
    const float* __restrict__ Dr, const float* __restrict__ Di,
    ushort_t* __restrict__ Afr, ushort_t* __restrict__ Afi,
    ushort_t* __restrict__ Atr, ushort_t* __restrict__ Ati,
    ushort_t* __restrict__ Dfr, ushort_t* __restrict__ Dfi,
    uint_t* __restrict__ syncbuf)
{
    const int gt = blockIdx.x * 256 + threadIdx.x;
    const int gs = gridDim.x * 256;
    for (int idx = gt; idx < SYNC_DW; idx += gs) syncbuf[idx] = 0u;
    for (int idx = gt; idx < L_ * 32768; idx += gs) {
        int j = idx & 7, rest = idx >> 3;
        int mm = rest & 15; rest >>= 4;
        int qq = rest & 3;  rest >>= 2;
        int k2 = rest & 1;  rest >>= 1;
        int tile = rest & 31;
        int l = rest >> 5;
        int t = tile * 16 + mm, k = k2 * 32 + qq * 8 + j;
        float vr = 0.f, vi = 0.f;
        if (k < 48) { int g = l * 24576 + t * 48 + k; vr = Ar[g]; vi = Ai[g]; }
        Afr[idx] = f2bf(vr); Afi[idx] = f2bf(vi);
    }
    for (int idx = gt; idx < L_ * 24576; idx += gs) {
        int j = idx & 7, rest = idx >> 3;
        int mm = rest & 15; rest >>= 4;
        int qq = rest & 3;  rest >>= 2;
        int ks = rest & 15; rest >>= 4;
        int ft = rest % 3;
        int l = rest / 3;
        int f = ft * 16 + mm, k = ks * 32 + qq * 8 + j;
        int g = l * 24576 + k * 48 + f;
        Atr[idx] = f2bf(Ar[g]); Ati[idx] = f2bf(Ai[g]);
    }
    for (int idx = gt; idx < 24576; idx += gs) {
        int j = idx & 7, rest = idx >> 3;
        int mm = rest & 15; rest >>= 4;
        int qq = rest & 3;  rest >>= 2;
        int ks = rest & 15;
        int ft = rest >> 4;
        int f = ft * 16 + mm, k = ks * 32 + qq * 8 + j;
        Dfr[idx] = f2bf(Dr[k * 48 + f]); Dfi[idx] = f2bf(Di[k * 48 + f]);
    }
}

// ---------- persistent cooperative kernel ----------
// 256 blocks x 512 threads; block owns rows [blk*32,+32).
// H lives in registers (f32); LDS holds z fp32 + Hn bf16 (bwd GEMM operand).
// Global sync: 8-line-spread atomic adds + block-0 collector + 8 replicated
// broadcast lines; exactly ONE thread per block touches sync lines.
__global__ __launch_bounds__(THR, 2) void k_lamp(
    const float* __restrict__ u,
    const ushort_t* __restrict__ Afr, const ushort_t* __restrict__ Afi,
    const ushort_t* __restrict__ Atr, const ushort_t* __restrict__ Ati,
    const ushort_t* __restrict__ Dfr, const ushort_t* __restrict__ Dfi,
    const float* __restrict__ th,
    uint_t* syncbuf,
    float* __restrict__ out)
{
    extern __shared__ char dyn[];
    float*    pR   = (float*)dyn;                  // [8][3][16][17] 26112 B
    float*    pI   = pR + 8 * 3 * 16 * 17;         // 26112 B
    float*    zreL = pI + 8 * 3 * 16 * 17;         // 6656 B
    float*    zimL = zreL + RPB * ZS;              // 6656 B
    float*    red  = zimL + RPB * ZS;              // 128 B (32 floats)
    ushort_t* HreL = (ushort_t*)(red + 32);        // 33280 B
    ushort_t* HimL = HreL + RPB * HST;             // 33280 B  => 132224 B

    uint_t* cnt8 = syncbuf;
    float*  bcF  = (float*)(syncbuf + 8 * LINE);
    float*  vals = bcF + 16 * 8 * LINE;

    const int tid = threadIdx.x, blk = blockIdx.x;
    const int row0 = blk * RPB;
    const int wave = tid >> 6, lane = tid & 63;
    const int quad = lane >> 4, m = lane & 15;
    const int rows16 = (wave >> 2) * 16;           // fwd: which 16-row tile
    const int rt = wave >> 2, kq = wave & 3;       // bwd: row-tile / K-quarter
    const float2* u2 = (const float2*)u;

    // sync event s: tid0 collects (blk 0) or polls; LDS-broadcast payload
    auto gsync = [&](int s, int nv) {
        if (tid == 0) {
            float2 v = (blk == 0)
                ? collect(cnt8, vals + s * 16 * LINE, bcF + s * 8 * LINE,
                          (uint_t)NBLK * (uint_t)(s + 1), nv)
                : waitbc(bcF + s * 8 * LINE + (blk & 7) * LINE);
            red[0] = v.x; red[1] = v.y;
        }
        __syncthreads();
        return make_float2(red[0], red[1]);
    };

    // persistent H fragments (f32): H[ct][reg] at (row=rows16+quad*4+reg, col=tile*16+m)
    f32x4 hR[8], hI[8];
    #pragma unroll
    for (int ct = 0; ct < 8; ++ct) { hR[ct] = (f32x4){0,0,0,0}; hI[ct] = (f32x4){0,0,0,0}; }

    // prologue: u -> z LDS, sigma partial -> sync slot 0
    float acc = 0.f;
    #pragma unroll
    for (int k3 = 0; k3 < 3; ++k3) {
        int j = tid + k3 * THR;
        int r = j / 48, c = j - r * 48;
        float2 v = u2[(row0 + r) * 48 + c];
        zreL[r * ZS + c] = v.x; zimL[r * ZS + c] = v.y;
        acc += v.x * v.x + v.y * v.y;
    }
    #pragma unroll
    for (int s = 32; s > 0; s >>= 1) acc += __shfl_xor(acc, s, 64);
    __syncthreads();                         // publishes z LDS
    if (lane == 0) red[8 + wave] = acc;
    __syncthreads();
    if (tid == 0) {
        float t = 0.f;
        #pragma unroll
        for (int w = 0; w < NW; ++w) t += red[8 + w];
        arrive(vals + 0, cnt8, blk, t, 0.f, 1);
    }

    for (int l = 0; l < L_; ++l) {
        // z A-frags from LDS fp32 (K=48 padded to 64)
        const float* zpr = zreL + (rows16 + m) * ZS;
        const float* zpi = zimL + (rows16 + m) * ZS;
        short8 zr0 = pack8(*(const float4*)(zpr + quad * 8), *(const float4*)(zpr + quad * 8 + 4));
        short8 zi0 = pack8(*(const float4*)(zpi + quad * 8), *(const float4*)(zpi + quad * 8 + 4));
        short8 zr1 = {0,0,0,0,0,0,0,0}, zi1 = {0,0,0,0,0,0,0,0};
        if (quad < 2) {
            zr1 = pack8(*(const float4*)(zpr + 32 + quad * 8), *(const float4*)(zpr + 36 + quad * 8));
            zi1 = pack8(*(const float4*)(zpi + 32 + quad * 8), *(const float4*)(zpi + 36 + quad * 8));
        }
        short8 zin0 = negbf(zi0), zin1 = negbf(zi1);

        // forward GEMM accumulating straight onto H_old (R = H + Z in registers)
        const ushort_t* Aflr = Afr + (size_t)l * 32768;
        const ushort_t* Afli = Afi + (size_t)l * 32768;
        #pragma unroll
        for (int ct = 0; ct < 8; ++ct) {
            const int tile = (wave & 3) * 8 + ct;
            const ushort_t* rp = Aflr + (size_t)(tile * 2) * 512 + lane * 8;
            const ushort_t* ip = Afli + (size_t)(tile * 2) * 512 + lane * 8;
            short8 ar0 = *(const short8*)rp;
            short8 ar1 = *(const short8*)(rp + 512);
            short8 ai0 = *(const short8*)ip;
            short8 ai1 = *(const short8*)(ip + 512);
            hR[ct] = MFMA(zr0, ar0, hR[ct]);
            hR[ct] = MFMA(zr1, ar1, hR[ct]);
            hR[ct] = MFMA(zin0, ai0, hR[ct]);
            hR[ct] = MFMA(zin1, ai1, hR[ct]);
            hI[ct] = MFMA(zr0, ai0, hI[ct]);
            hI[ct] = MFMA(zr1, ai1, hI[ct]);
            hI[ct] = MFMA(zi0, ar0, hI[ct]);
            hI[ct] = MFMA(zi1, ar1, hI[ct]);
        }

        // sigma sync (hidden behind the GEMM above): event s = 2l
        float2 sv = gsync(2 * l, 1);
        const float lam = th[l * 3] * sqrtf(sv.x * (1.0f / 48.0f));
        const float th1 = th[l * 3 + 1];

        // activation on registers: Hn = act(R); store Hn bf16 to LDS for bwd GEMM
        float cr = 0.f, ci = 0.f;
        #pragma unroll
        for (int ct = 0; ct < 8; ++ct) {
            const int t = ((wave & 3) * 8 + ct) * 16 + m;
            #pragma unroll
            for (int reg = 0; reg < 4; ++reg) {
                const int lr = rows16 + quad * 4 + reg;
                float Rr = hR[ct][reg], Ri = hI[ct][reg];
                float mr = fabsf(Rr), mi = fabsf(Ri);
                float fr = th1 * copysignf(fmaxf(mr - lam, 0.f), Rr);
                float fi = th1 * copysignf(fmaxf(mi - lam, 0.f), Ri);
                cr += (mr > lam) ? 1.f : 0.f;
                ci += (mi > lam) ? 1.f : 0.f;
                hR[ct][reg] = fr; hI[ct][reg] = fi;
                HreL[lr * HST + t] = f2bf(fr);
                HimL[lr * HST + t] = f2bf(fi);
            }
        }

        if (l == L_ - 1) { __syncthreads(); break; }   // publish Hn for final GEMM

        // reduce (cr,ci) in-block, arrive at b event s = 2l+1
        #pragma unroll
        for (int s = 32; s > 0; s >>= 1) { cr += __shfl_xor(cr, s, 64); ci += __shfl_xor(ci, s, 64); }
        __syncthreads();                               // also publishes Hn LDS
        if (lane == 0) { red[8 + wave] = cr; red[16 + wave] = ci; }
        __syncthreads();
        if (tid == 0) {
            float tr = 0.f, tii = 0.f;
            #pragma unroll
            for (int w = 0; w < NW; ++w) { tr += red[8 + w]; tii += red[16 + w]; }
            arrive(vals + (2 * l + 1) * 16 * LINE, cnt8, blk, tr, tii, 2);
        }

        // backward GEMM: h = Hn @ A; wave (rt,kq) does rows rt*16..+16, K quarter kq
        const ushort_t* Atlr = Atr + (size_t)l * 24576;
        const ushort_t* Atli = Ati + (size_t)l * 24576;
        f32x4 aR[3], aI[3];
        #pragma unroll
        for (int q = 0; q < 3; ++q) { aR[q] = (f32x4){0,0,0,0}; aI[q] = (f32x4){0,0,0,0}; }
        #pragma unroll
        for (int ks = 0; ks < 4; ++ks) {
            const int ksa = kq * 4 + ks;
            const int k0 = ksa * 32 + quad * 8;
            short8 hr = *(const short8*)&HreL[(rt * 16 + m) * HST + k0];
            short8 hi = *(const short8*)&HimL[(rt * 16 + m) * HST + k0];
            short8 hin = negbf(hi);
            #pragma unroll
            for (int ft = 0; ft < 3; ++ft) {
                short8 br = *(const short8*)(Atlr + (size_t)((ft * 16 + ksa) * 64 + lane) * 8);
                short8 bi = *(const short8*)(Atli + (size_t)((ft * 16 + ksa) * 64 + lane) * 8);
                aR[ft] = MFMA(hr, br, aR[ft]);
                aR[ft] = MFMA(hin, bi, aR[ft]);
                aI[ft] = MFMA(hr, bi, aI[ft]);
                aI[ft] = MFMA(hi, br, aI[ft]);
            }
        }
        #pragma unroll
        for (int ft = 0; ft < 3; ++ft) {
            #pragma unroll
            for (int reg = 0; reg < 4; ++reg) {
                pR[((wave * 3 + ft) * 16 + quad * 4 + reg) * 17 + m] = aR[ft][reg];
                pI[((wave * 3 + ft) * 16 + quad * 4 + reg) * 17 + m] = aI[ft][reg];
            }
        }

        // b sync (hidden behind backward GEMM); its syncthreads publishes pR/pI
        float2 bv = gsync(2 * l + 1, 2);
        const float bre = th1 * bv.x * (1.0f / 48.0f);
        const float bim = th1 * bv.y * (1.0f / 48.0f);

        // z update + sigma partial -> event s = 2l+2
        float nrm = 0.f;
        #pragma unroll
        for (int k3 = 0; k3 < 3; ++k3) {
            int j = tid + k3 * THR;
            int r = j / 48, f = j - r * 48;
            int rt2 = r >> 4, lr = r & 15, ft = f >> 4, c = f & 15;
            float hRv = 0.f, hIv = 0.f;
            #pragma unroll
            for (int q = 0; q < 4; ++q) {
                hRv += pR[(((rt2 * 4 + q) * 3 + ft) * 16 + lr) * 17 + c];
                hIv += pI[(((rt2 * 4 + q) * 3 + ft) * 16 + lr) * 17 + c];
            }
            float2 uv = u2[(row0 + r) * 48 + f];
            float zr = zreL[r * ZS + f], zi = zimL[r * ZS + f];
            float znr = uv.x - hRv + bre * zr;
            float zni = uv.y - hIv + bim * zi;
            zreL[r * ZS + f] = znr; zimL[r * ZS + f] = zni;
            nrm += znr * znr + zni * zni;
        }
        #pragma unroll
        for (int s = 32; s > 0; s >>= 1) nrm += __shfl_xor(nrm, s, 64);
        __syncthreads();                 // z published for next fwd GEMM
        if (lane == 0) red[8 + wave] = nrm;
        __syncthreads();
        if (tid == 0) {
            float t = 0.f;
            #pragma unroll
            for (int w = 0; w < NW; ++w) t += red[8 + w];
            arrive(vals + (2 * l + 2) * 16 * LINE, cnt8, blk, t, 0.f, 1);
        }
    }

    // final: out = Hn(LDS) @ DFT  (wave (rt,kq), K-split, LDS combine)
    f32x4 fR[3], fI[3];
    #pragma unroll
    for (int q = 0; q < 3; ++q) { fR[q] = (f32x4){0,0,0,0}; fI[q] = (f32x4){0,0,0,0}; }
    #pragma unroll
    for (int ks = 0; ks < 4; ++ks) {
        const int ksa = kq * 4 + ks;
        const int k0 = ksa * 32 + quad * 8;
        short8 hr = *(const short8*)&HreL[(rt * 16 + m) * HST + k0];
        short8 hi = *(const short8*)&HimL[(rt * 16 + m) * HST + k0];
        short8 hin = negbf(hi);
        #pragma unroll
        for (int ft = 0; ft < 3; ++ft) {
            short8 br = *(const short8*)(Dfr + (size_t)((ft * 16 + ksa) * 64 + lane) * 8);
            short8 bi = *(const short8*)(Dfi + (size_t)((ft * 16 + ksa) * 64 + lane) * 8);
            fR[ft] = MFMA(hr, br, fR[ft]);
            fR[ft] = MFMA(hin, bi, fR[ft]);
            fI[ft] = MFMA(hr, bi, fI[ft]);
            fI[ft] = MFMA(hi, br, fI[ft]);
        }
    }
    #pragma unroll
    for (int ft = 0; ft < 3; ++ft) {
        #pragma unroll
        for (int reg = 0; reg < 4; ++reg) {
            pR[((wave * 3 + ft) * 16 + quad * 4 + reg) * 17 + m] = fR[ft][reg];
            pI[((wave * 3 + ft) * 16 + quad * 4 + reg) * 17 + m] = fI[ft][reg];
        }
    }
    __syncthreads();
    float2* out2 = (float2*)out;
    #pragma unroll
    for (int k3 = 0; k3 < 3; ++k3) {
        int j = tid + k3 * THR;
        int r = j / 48, f = j - r * 48;
        int rt2 = r >> 4, lr = r & 15, ft = f >> 4, c = f & 15;
        float hRv = 0.f, hIv = 0.f;
        #pragma unroll
        for (int q = 0; q < 4; ++q) {
            hRv += pR[(((rt2 * 4 + q) * 3 + ft) * 16 + lr) * 17 + c];
            hIv += pI[(((rt2 * 4 + q) * 3 + ft) * 16 + lr) * 17 + c];
        }
        out2[(row0 + r) * 48 + f] = make_float2(hRv, hIv);
    }
}

extern "C" void kernel_launch(void* const* d_in, const int* in_sizes, int n_in,
                              void* d_out, int out_size, void* d_ws, size_t ws_size,
                              hipStream_t stream) {
    (void)in_sizes; (void)n_in; (void)out_size; (void)ws_size;
    const float* u  = (const float*)d_in[0];
    const float* Ar = (const float*)d_in[1];
    const float* Ai = (const float*)d_in[2];
    const float* th = (const float*)d_in[3];
    const float* Dr = (const float*)d_in[4];
    const float* Di = (const float*)d_in[5];
    float* out = (float*)d_out;

    char* p = (char*)d_ws;
    auto alloc = [&](size_t bytes) -> char* {
        char* r = p;
        p += (bytes + 255) & ~(size_t)255;
        return r;
    };
    uint_t*   syncbuf = (uint_t*)alloc(SYNC_DW * 4);
    ushort_t* Afr = (ushort_t*)alloc((size_t)L_ * 32768 * 2);
    ushort_t* Afi = (ushort_t*)alloc((size_t)L_ * 32768 * 2);
    ushort_t* Atr = (ushort_t*)alloc((size_t)L_ * 24576 * 2);
    ushort_t* Ati = (ushort_t*)alloc((size_t)L_ * 24576 * 2);
    ushort_t* Dfr = (ushort_t*)alloc((size_t)24576 * 2);
    ushort_t* Dfi = (ushort_t*)alloc((size_t)24576 * 2);

    k_pre<<<1024, 256, 0, stream>>>(Ar, Ai, Dr, Di, Afr, Afi, Atr, Ati, Dfr, Dfi, syncbuf);

    const uint_t lds_bytes = 132224;
    hipFuncSetAttribute((const void*)k_lamp,
                        hipFuncAttributeMaxDynamicSharedMemorySize, (int)lds_bytes);
    void* args[] = { (void*)&u, (void*)&Afr, (void*)&Afi, (void*)&Atr, (void*)&Ati,
                     (void*)&Dfr, (void*)&Dfi, (void*)&th,
                     (void*)&syncbuf, (void*)&out };
    hipLaunchCooperativeKernel((void*)k_lamp, dim3(NBLK), dim3(THR), args,
                               lds_bytes, stream);
}